// Round 9
// baseline (153.747 us; speedup 1.0000x reference)
//
#include <hip/hip_runtime.h>

#define D 128
#define NCG 4      // 32-col slices; slice = 50000*64B = 3.2 MB < 4 MiB XCD L2

typedef __attribute__((ext_vector_type(8))) short short8;   // 8 bf16 (4 VGPRs)
typedef __attribute__((ext_vector_type(4))) float floatx4;  // MFMA acc

__device__ __forceinline__ float bf_lo(unsigned u) { return __uint_as_float(u << 16); }
__device__ __forceinline__ float bf_hi(unsigned u) { return __uint_as_float(u & 0xffff0000u); }
__device__ __forceinline__ unsigned pack_bf16(float a, float b) {
    unsigned ua = __float_as_uint(a), ub = __float_as_uint(b);
    ua = (ua + 0x7fffu + ((ua >> 16) & 1u)) >> 16;   // RNE
    ub = (ub + 0x7fffu + ((ub >> 16) & 1u)) >> 16;
    return ua | (ub << 16);
}

// ---------------------------------------------------------------------------
// Fused prep: [A] features f32->bf16 into Fb[cg][node][32cols] slices |
// [B] packed (ij,w) u64 records + seg offsets | [C] W -> Wt bf16 transposed.
// ---------------------------------------------------------------------------
__global__ __launch_bounds__(256) void prep_kernel(
    const float* __restrict__ F, const float* __restrict__ pw,
    const float* __restrict__ W, const int* __restrict__ pi,
    const int* __restrict__ pj, const int* __restrict__ nidx,
    unsigned* __restrict__ Fb, unsigned long long* __restrict__ rec,
    int* __restrict__ offs, unsigned* __restrict__ Wt,
    int n_nodes, int n_pairs) {
    const int B1 = (n_nodes * (D / 4) + 255) / 256;
    const int B2 = (n_pairs + 255) / 256;
    const int b = blockIdx.x;
    if (b < B1) {                       // features -> bf16, sliced layout
        int t = b * 256 + threadIdx.x;  // one t per 4 cols
        if (t >= n_nodes * (D / 4)) return;
        int n = t >> 5, q = t & 31;
        float4 v = reinterpret_cast<const float4*>(F)[t];
        uint2 o = {pack_bf16(v.x, v.y), pack_bf16(v.z, v.w)};
        int cg = q >> 3, qq = q & 7;    // slice-row = 16 uints = 8 uint2
        reinterpret_cast<uint2*>(Fb + (size_t)(cg * n_nodes + n) * 16)[qq] = o;
    } else if (b < B1 + B2) {           // records + offsets
        int p = (b - B1) * 256 + threadIdx.x;
        if (p >= n_pairs) return;
        unsigned ijv = (unsigned)pi[p] | ((unsigned)pj[p] << 16);
        rec[p] = (unsigned long long)ijv |
                 ((unsigned long long)__float_as_uint(pw[p]) << 32);
        int cur  = nidx[p];
        int prev = p ? nidx[p - 1] : -1;
        for (int n = prev + 1; n <= cur; ++n) offs[n] = p;
        if (p == n_pairs - 1)
            for (int n = cur + 1; n <= n_nodes; ++n) offs[n] = n_pairs;
    } else {                            // Wt[c][kk] = pack(W[2kk][c], W[2kk+1][c])
        int t = (b - B1 - B2) * 256 + threadIdx.x;
        if (t >= D * (D / 2)) return;
        int c = t >> 6, kk = t & 63;
        Wt[t] = pack_bf16(W[(2 * kk) * D + c], W[(2 * kk + 1) * D + c]);
    }
}

// ---------------------------------------------------------------------------
// Aggregate: wave per (node, cg). cg = blockIdx&3 -> XCD-pinned 3.2 MB slice
// (L2-resident: R3 measured fetch 306->91 MB with this footprint). Wave =
// 16 groups x 4 lanes; lane gathers uint4 = 16 B (4 lanes cover the 64 B
// slice-row). Group g takes pairs start+g, start+g+16, ... Simple dependent
// loop (R8 chunk-unroll regressed). Butterfly reduce over lane bits 2..5.
// ---------------------------------------------------------------------------
__global__ __launch_bounds__(256) void aggregate_kernel(
    const unsigned* __restrict__ Fb, const unsigned long long* __restrict__ rec,
    const int* __restrict__ offs, unsigned* __restrict__ aggb, int n_nodes) {
    const int cg  = blockIdx.x & (NCG - 1);
    const int wid = threadIdx.x >> 6;
    const int n   = (blockIdx.x >> 2) * 4 + wid;
    if (n >= n_nodes) return;
    const int start = offs[n];
    const int end   = offs[n + 1];
    const int lane  = threadIdx.x & 3;         // 4 lanes x 16B = 64B slice-row
    const int g     = (threadIdx.x >> 2) & 15; // 16 groups, stride 16 over pairs

    const unsigned* __restrict__ base = Fb + (size_t)cg * n_nodes * 16 + lane * 4;

    float a0 = 0.f, a1 = 0.f, a2 = 0.f, a3 = 0.f;
    float a4 = 0.f, a5 = 0.f, a6 = 0.f, a7 = 0.f;

    for (int p = start + g; p < end; p += 16) {
        const unsigned long long r = __builtin_nontemporal_load(rec + p);
        const unsigned ij_ = (unsigned)r;
        const unsigned i_  = ij_ & 0xffffu;
        const unsigned j_  = ij_ >> 16;
        const float    w_  = __uint_as_float((unsigned)(r >> 32));
        const uint4 ui = *reinterpret_cast<const uint4*>(base + (size_t)i_ * 16);
        const uint4 uj = *reinterpret_cast<const uint4*>(base + (size_t)j_ * 16);
        a0 += (bf_lo(ui.x) + bf_lo(uj.x)) * w_;
        a1 += (bf_hi(ui.x) + bf_hi(uj.x)) * w_;
        a2 += (bf_lo(ui.y) + bf_lo(uj.y)) * w_;
        a3 += (bf_hi(ui.y) + bf_hi(uj.y)) * w_;
        a4 += (bf_lo(ui.z) + bf_lo(uj.z)) * w_;
        a5 += (bf_hi(ui.z) + bf_hi(uj.z)) * w_;
        a6 += (bf_lo(ui.w) + bf_lo(uj.w)) * w_;
        a7 += (bf_hi(ui.w) + bf_hi(uj.w)) * w_;
    }

#pragma unroll
    for (int m = 4; m <= 32; m <<= 1) {
        a0 += __shfl_xor(a0, m); a1 += __shfl_xor(a1, m);
        a2 += __shfl_xor(a2, m); a3 += __shfl_xor(a3, m);
        a4 += __shfl_xor(a4, m); a5 += __shfl_xor(a5, m);
        a6 += __shfl_xor(a6, m); a7 += __shfl_xor(a7, m);
    }

    if (g == 0) {
        uint4 o = {pack_bf16(a0, a1), pack_bf16(a2, a3),
                   pack_bf16(a4, a5), pack_bf16(a6, a7)};
        *reinterpret_cast<uint4*>(aggb + (size_t)n * 64 + cg * 16 + lane * 4) = o;
    }
}

// ---------------------------------------------------------------------------
// Proj (MFMA): out = aggb(bf16) @ W + bias, f32 acc via mfma_f32_16x16x32_bf16.
// (validated R6). Block = 4 waves x 16 rows.
// ---------------------------------------------------------------------------
__global__ __launch_bounds__(256) void proj_kernel(
    const unsigned* __restrict__ aggb, const unsigned* __restrict__ Wt,
    const float* __restrict__ bias, float* __restrict__ out, int M) {
    const int wid = threadIdx.x >> 6;
    const int l   = threadIdx.x & 63;
    const int lr  = l & 15;
    const int lk  = l >> 4;
    const int row_base = blockIdx.x * 64 + wid * 16;

    int arow = row_base + lr;
    if (arow >= M) arow = M - 1;  // clamp; stores predicated

    const short8* __restrict__ A8 = reinterpret_cast<const short8*>(aggb);
    const short8* __restrict__ B8 = reinterpret_cast<const short8*>(Wt);

    floatx4 acc[8];
#pragma unroll
    for (int t = 0; t < 8; ++t) acc[t] = (floatx4){0.f, 0.f, 0.f, 0.f};

#pragma unroll
    for (int ks = 0; ks < 4; ++ks) {
        const short8 a = A8[(size_t)arow * 16 + ks * 4 + lk];
#pragma unroll
        for (int t = 0; t < 8; ++t) {
            const short8 bfr = B8[(size_t)(t * 16 + lr) * 16 + ks * 4 + lk];
            acc[t] = __builtin_amdgcn_mfma_f32_16x16x32_bf16(a, bfr, acc[t], 0, 0, 0);
        }
    }

#pragma unroll
    for (int t = 0; t < 8; ++t) {
        const float bcol = bias[t * 16 + lr];
#pragma unroll
        for (int r = 0; r < 4; ++r) {
            const int row = row_base + lk * 4 + r;
            if (row < M)
                out[(size_t)row * D + t * 16 + lr] = acc[t][r] + bcol;
        }
    }
}

// ---------------------------------------------------------------------------
extern "C" void kernel_launch(void* const* d_in, const int* in_sizes, int n_in,
                              void* d_out, int out_size, void* d_ws, size_t ws_size,
                              hipStream_t stream) {
    const float* F    = (const float*)d_in[0];
    const float* pw   = (const float*)d_in[1];
    const float* W    = (const float*)d_in[2];
    const float* bias = (const float*)d_in[3];
    const int*   pi   = (const int*)d_in[4];
    const int*   pj   = (const int*)d_in[5];
    const int*   nidx = (const int*)d_in[6];
    float* out = (float*)d_out;

    const int n_pairs = in_sizes[1];
    const int n_nodes = in_sizes[0] / D;

    // ws layout: aggb | offs | rec | Wt | [Fb]
    const size_t aggb_bytes = (size_t)n_nodes * D * 2;
    const size_t offs_bytes = ((size_t)(n_nodes + 1) * 4 + 255) & ~(size_t)255;
    const size_t rec_bytes  = (size_t)n_pairs * 8;
    const size_t wt_bytes   = (size_t)D * (D / 2) * 4;
    const size_t fb_bytes   = (size_t)n_nodes * D * 2;

    char* pp = (char*)d_ws;
    unsigned* aggb = (unsigned*)pp;                pp += aggb_bytes;
    int*      offs = (int*)pp;                     pp += offs_bytes;
    unsigned long long* rec = (unsigned long long*)pp;  pp += rec_bytes;
    unsigned* Wt   = (unsigned*)pp;                pp += wt_bytes;
    size_t used = (size_t)(pp - (char*)d_ws);
    unsigned* Fb = (ws_size >= used + fb_bytes)
                 ? (unsigned*)pp
                 : (unsigned*)d_out;  // proj writes out last; Fb dead by then

    const int B1 = (n_nodes * (D / 4) + 255) / 256;
    const int B2 = (n_pairs + 255) / 256;
    const int B3 = (D * (D / 2) + 255) / 256;
    prep_kernel<<<B1 + B2 + B3, 256, 0, stream>>>(F, pw, W, pi, pj, nidx,
                                                  Fb, rec, offs, Wt,
                                                  n_nodes, n_pairs);
    const int nb = (n_nodes + 3) / 4;  // 4 node-waves per block
    aggregate_kernel<<<nb * NCG, 256, 0, stream>>>(Fb, rec, offs, aggb, n_nodes);
    proj_kernel<<<(n_nodes + 63) / 64, 256, 0, stream>>>(aggb, Wt, bias, out, n_nodes);
}

// Round 10
// 133.260 us; speedup vs baseline: 1.1537x; 1.1537x over previous
//
#include <hip/hip_runtime.h>

#define D 128

typedef __attribute__((ext_vector_type(8))) short short8;   // 8 bf16 (4 VGPRs)
typedef __attribute__((ext_vector_type(4))) float floatx4;  // MFMA acc

__device__ __forceinline__ float bf_lo(unsigned u) { return __uint_as_float(u << 16); }
__device__ __forceinline__ float bf_hi(unsigned u) { return __uint_as_float(u & 0xffff0000u); }
__device__ __forceinline__ unsigned pack_bf16(float a, float b) {
    unsigned ua = __float_as_uint(a), ub = __float_as_uint(b);
    ua = (ua + 0x7fffu + ((ua >> 16) & 1u)) >> 16;   // RNE
    ub = (ub + 0x7fffu + ((ub >> 16) & 1u)) >> 16;
    return ua | (ub << 16);
}

// ---------------------------------------------------------------------------
// Prep (lean): [A] features f32->bf16, plain [node][128] layout |
// [B] segment offsets from sorted nidx | [C] W -> Wt bf16 transposed.
// No record packing (R6 showed index-load traffic is timing-neutral in
// aggregate; saves a 12.8 MB round-trip + 19.2 MB of prep reads).
// ---------------------------------------------------------------------------
__global__ __launch_bounds__(256) void prep_kernel(
    const float* __restrict__ F, const float* __restrict__ W,
    const int* __restrict__ nidx,
    unsigned* __restrict__ Fb, int* __restrict__ offs, unsigned* __restrict__ Wt,
    int n_nodes, int n_pairs) {
    const int B1 = (n_nodes * (D / 4) + 255) / 256;
    const int B2 = (n_pairs + 255) / 256;
    const int b = blockIdx.x;
    if (b < B1) {                       // features -> bf16
        int t = b * 256 + threadIdx.x;
        if (t >= n_nodes * (D / 4)) return;
        float4 v = reinterpret_cast<const float4*>(F)[t];
        uint2 o = {pack_bf16(v.x, v.y), pack_bf16(v.z, v.w)};
        reinterpret_cast<uint2*>(Fb)[t] = o;
    } else if (b < B1 + B2) {           // segment offsets
        int p = (b - B1) * 256 + threadIdx.x;
        if (p >= n_pairs) return;
        int cur  = nidx[p];
        int prev = p ? nidx[p - 1] : -1;
        for (int n = prev + 1; n <= cur; ++n) offs[n] = p;
        if (p == n_pairs - 1)
            for (int n = cur + 1; n <= n_nodes; ++n) offs[n] = n_pairs;
    } else {                            // Wt[c][kk] = pack(W[2kk][c], W[2kk+1][c])
        int t = (b - B1 - B2) * 256 + threadIdx.x;
        if (t >= D * (D / 2)) return;
        int c = t >> 6, kk = t & 63;
        Wt[t] = pack_bf16(W[(2 * kk) * D + c], W[(2 * kk + 1) * D + c]);
    }
}

// ---------------------------------------------------------------------------
// Aggregate (R6 structure — best measured: 71 µs, ~11.5 TB/s L2 gather
// demand ≈ per-CU outstanding-line plateau). Wave per (node, half-row cg);
// cg = blockIdx&1 -> XCD-pinned alternating 128B lines. 8 groups x 8 lanes;
// lane gathers uint4 = 16 B. Indices read directly (pi/pj/pw), group-uniform.
// Simple dependent loop (R8 unrolling regressed via VGPR/occupancy).
// Butterfly reduce over lane bits 3..5; zero LDS, zero syncthreads.
// ---------------------------------------------------------------------------
__global__ __launch_bounds__(256) void aggregate_kernel(
    const unsigned* __restrict__ Fb, const int* __restrict__ pi,
    const int* __restrict__ pj, const float* __restrict__ pw,
    const int* __restrict__ offs, unsigned* __restrict__ aggb, int n_nodes) {
    const int cg  = blockIdx.x & 1;
    const int wid = threadIdx.x >> 6;
    const int n   = (blockIdx.x >> 1) * 4 + wid;
    if (n >= n_nodes) return;
    const int start = offs[n];
    const int end   = offs[n + 1];
    const int lane  = threadIdx.x & 7;
    const int g     = (threadIdx.x >> 3) & 7;

    const unsigned* __restrict__ base = Fb + cg * 32 + lane * 4;  // uint units

    float a0 = 0.f, a1 = 0.f, a2 = 0.f, a3 = 0.f;
    float a4 = 0.f, a5 = 0.f, a6 = 0.f, a7 = 0.f;

    for (int p = start + g; p < end; p += 8) {
        const unsigned i_ = (unsigned)__builtin_nontemporal_load(pi + p);
        const unsigned j_ = (unsigned)__builtin_nontemporal_load(pj + p);
        const float    w_ = __builtin_nontemporal_load(pw + p);
        const uint4 ui = *reinterpret_cast<const uint4*>(base + (size_t)i_ * 64);
        const uint4 uj = *reinterpret_cast<const uint4*>(base + (size_t)j_ * 64);
        a0 += (bf_lo(ui.x) + bf_lo(uj.x)) * w_;
        a1 += (bf_hi(ui.x) + bf_hi(uj.x)) * w_;
        a2 += (bf_lo(ui.y) + bf_lo(uj.y)) * w_;
        a3 += (bf_hi(ui.y) + bf_hi(uj.y)) * w_;
        a4 += (bf_lo(ui.z) + bf_lo(uj.z)) * w_;
        a5 += (bf_hi(ui.z) + bf_hi(uj.z)) * w_;
        a6 += (bf_lo(ui.w) + bf_lo(uj.w)) * w_;
        a7 += (bf_hi(ui.w) + bf_hi(uj.w)) * w_;
    }

#pragma unroll
    for (int m = 8; m <= 32; m <<= 1) {
        a0 += __shfl_xor(a0, m); a1 += __shfl_xor(a1, m);
        a2 += __shfl_xor(a2, m); a3 += __shfl_xor(a3, m);
        a4 += __shfl_xor(a4, m); a5 += __shfl_xor(a5, m);
        a6 += __shfl_xor(a6, m); a7 += __shfl_xor(a7, m);
    }

    if (g == 0) {
        uint4 o = {pack_bf16(a0, a1), pack_bf16(a2, a3),
                   pack_bf16(a4, a5), pack_bf16(a6, a7)};
        *reinterpret_cast<uint4*>(aggb + (size_t)n * 64 + cg * 32 + lane * 4) = o;
    }
}

// ---------------------------------------------------------------------------
// Proj (MFMA): out = aggb(bf16) @ W + bias via mfma_f32_16x16x32_bf16.
// (validated R6/R8). Block = 4 waves x 16 rows.
// ---------------------------------------------------------------------------
__global__ __launch_bounds__(256) void proj_kernel(
    const unsigned* __restrict__ aggb, const unsigned* __restrict__ Wt,
    const float* __restrict__ bias, float* __restrict__ out, int M) {
    const int wid = threadIdx.x >> 6;
    const int l   = threadIdx.x & 63;
    const int lr  = l & 15;
    const int lk  = l >> 4;
    const int row_base = blockIdx.x * 64 + wid * 16;

    int arow = row_base + lr;
    if (arow >= M) arow = M - 1;  // clamp; stores predicated

    const short8* __restrict__ A8 = reinterpret_cast<const short8*>(aggb);
    const short8* __restrict__ B8 = reinterpret_cast<const short8*>(Wt);

    floatx4 acc[8];
#pragma unroll
    for (int t = 0; t < 8; ++t) acc[t] = (floatx4){0.f, 0.f, 0.f, 0.f};

#pragma unroll
    for (int ks = 0; ks < 4; ++ks) {
        const short8 a = A8[(size_t)arow * 16 + ks * 4 + lk];
#pragma unroll
        for (int t = 0; t < 8; ++t) {
            const short8 bfr = B8[(size_t)(t * 16 + lr) * 16 + ks * 4 + lk];
            acc[t] = __builtin_amdgcn_mfma_f32_16x16x32_bf16(a, bfr, acc[t], 0, 0, 0);
        }
    }

#pragma unroll
    for (int t = 0; t < 8; ++t) {
        const float bcol = bias[t * 16 + lr];
#pragma unroll
        for (int r = 0; r < 4; ++r) {
            const int row = row_base + lk * 4 + r;
            if (row < M)
                out[(size_t)row * D + t * 16 + lr] = acc[t][r] + bcol;
        }
    }
}

// ---------------------------------------------------------------------------
extern "C" void kernel_launch(void* const* d_in, const int* in_sizes, int n_in,
                              void* d_out, int out_size, void* d_ws, size_t ws_size,
                              hipStream_t stream) {
    const float* F    = (const float*)d_in[0];
    const float* pw   = (const float*)d_in[1];
    const float* W    = (const float*)d_in[2];
    const float* bias = (const float*)d_in[3];
    const int*   pi   = (const int*)d_in[4];
    const int*   pj   = (const int*)d_in[5];
    const int*   nidx = (const int*)d_in[6];
    float* out = (float*)d_out;

    const int n_pairs = in_sizes[1];
    const int n_nodes = in_sizes[0] / D;

    // ws layout: aggb | offs | Wt | [Fb]
    const size_t aggb_bytes = (size_t)n_nodes * D * 2;
    const size_t offs_bytes = ((size_t)(n_nodes + 1) * 4 + 255) & ~(size_t)255;
    const size_t wt_bytes   = (size_t)D * (D / 2) * 4;
    const size_t fb_bytes   = (size_t)n_nodes * D * 2;

    char* pp = (char*)d_ws;
    unsigned* aggb = (unsigned*)pp;   pp += aggb_bytes;
    int*      offs = (int*)pp;        pp += offs_bytes;
    unsigned* Wt   = (unsigned*)pp;   pp += wt_bytes;
    size_t used = (size_t)(pp - (char*)d_ws);
    unsigned* Fb = (ws_size >= used + fb_bytes)
                 ? (unsigned*)pp
                 : (unsigned*)d_out;  // proj writes out last; Fb dead by then

    const int B1 = (n_nodes * (D / 4) + 255) / 256;
    const int B2 = (n_pairs + 255) / 256;
    const int B3 = (D * (D / 2) + 255) / 256;
    prep_kernel<<<B1 + B2 + B3, 256, 0, stream>>>(F, W, nidx, Fb, offs, Wt,
                                                  n_nodes, n_pairs);
    const int nb = (n_nodes + 3) / 4;  // 4 node-waves per block
    aggregate_kernel<<<nb * 2, 256, 0, stream>>>(Fb, pi, pj, pw, offs, aggb, n_nodes);
    proj_kernel<<<(n_nodes + 63) / 64, 256, 0, stream>>>(aggb, Wt, bias, out, n_nodes);
}

// Round 12
// 127.119 us; speedup vs baseline: 1.2095x; 1.0483x over previous
//
#include <hip/hip_runtime.h>

#define D 128
typedef unsigned long long ull;

typedef __attribute__((ext_vector_type(8))) short short8;   // 8 bf16 (4 VGPRs)
typedef __attribute__((ext_vector_type(4))) float floatx4;  // MFMA acc

__device__ __forceinline__ unsigned pack_bf16(float a, float b) {
    unsigned ua = __float_as_uint(a), ub = __float_as_uint(b);
    ua = (ua + 0x7fffu + ((ua >> 16) & 1u)) >> 16;   // RNE
    ub = (ub + 0x7fffu + ((ub >> 16) & 1u)) >> 16;
    return ua | (ub << 16);
}

// acc += pk.lo * wd.lo + pk.hi * wd.hi   (bf16 x bf16 -> f32 dot2)
#define DOT2(acc, pk, wd)                                                   \
    asm("v_dot2_f32_bf16 %0, %1, %2, %0" : "+v"(acc) : "v"(pk), "v"(wd));

// ---------------------------------------------------------------------------
// Prep: [A] features f32->bf16 [node][128] | [B] rec = i | j<<16 | wdup<<32
// (wdup = bf16(w) duplicated -> ready-made v_dot2 operand) + seg offsets |
// [C] W -> Wt bf16 transposed ([col][k-pairs]).
// ---------------------------------------------------------------------------
__global__ __launch_bounds__(256) void prep_kernel(
    const float* __restrict__ F, const float* __restrict__ pw,
    const float* __restrict__ W, const int* __restrict__ pi,
    const int* __restrict__ pj, const int* __restrict__ nidx,
    unsigned* __restrict__ Fb, ull* __restrict__ rec,
    int* __restrict__ offs, unsigned* __restrict__ Wt,
    int n_nodes, int n_pairs) {
    const int B1 = (n_nodes * (D / 4) + 255) / 256;
    const int B2 = (n_pairs + 255) / 256;
    const int b = blockIdx.x;
    if (b < B1) {                       // features -> bf16
        int t = b * 256 + threadIdx.x;
        if (t >= n_nodes * (D / 4)) return;
        float4 v = reinterpret_cast<const float4*>(F)[t];
        uint2 o = {pack_bf16(v.x, v.y), pack_bf16(v.z, v.w)};
        reinterpret_cast<uint2*>(Fb)[t] = o;
    } else if (b < B1 + B2) {           // records + offsets
        int p = (b - B1) * 256 + threadIdx.x;
        if (p >= n_pairs) return;
        unsigned wb = __float_as_uint(pw[p]);
        wb = (wb + 0x7fffu + ((wb >> 16) & 1u)) >> 16;
        unsigned wdup = wb | (wb << 16);
        rec[p] = (ull)((unsigned)pi[p] | ((unsigned)pj[p] << 16)) | ((ull)wdup << 32);
        int cur  = nidx[p];
        int prev = p ? nidx[p - 1] : -1;
        for (int n = prev + 1; n <= cur; ++n) offs[n] = p;
        if (p == n_pairs - 1)
            for (int n = cur + 1; n <= n_nodes; ++n) offs[n] = n_pairs;
    } else {                            // Wt[c][kk] = pack(W[2kk][c], W[2kk+1][c])
        int t = (b - B1 - B2) * 256 + threadIdx.x;
        if (t >= D * (D / 2)) return;
        int c = t >> 6, kk = t & 63;
        Wt[t] = pack_bf16(W[(2 * kk) * D + c], W[(2 * kk + 1) * D + c]);
    }
}

// ---------------------------------------------------------------------------
// Aggregate (R6 structure, dot2 inner loop). Wave per (node, half-row cg);
// cg = blockIdx&1 -> XCD-pinned alternating 128B lines (best measured).
// 8 groups x 8 lanes; lane gathers uint4 = 16 B (8 bf16 cols) per side.
// Per 2 cols: 2x v_perm pack [fj_c:fi_c] + 2x v_dot2_f32_bf16 with wdup —
// 16 VALU/pair/lane vs 32 for unpack+add+fma (R6). Butterfly reduce,
// zero LDS, zero syncthreads. Output bf16.
// ---------------------------------------------------------------------------
__global__ __launch_bounds__(256) void aggregate_kernel(
    const unsigned* __restrict__ Fb, const ull* __restrict__ rec,
    const int* __restrict__ offs, unsigned* __restrict__ aggb, int n_nodes) {
    const int cg  = blockIdx.x & 1;
    const int wid = threadIdx.x >> 6;
    const int n   = (blockIdx.x >> 1) * 4 + wid;
    if (n >= n_nodes) return;
    const int start = offs[n];
    const int end   = offs[n + 1];
    const int lane  = threadIdx.x & 7;
    const int g     = (threadIdx.x >> 3) & 7;

    const unsigned* __restrict__ base = Fb + cg * 32 + lane * 4;  // uint units

    float a0 = 0.f, a1 = 0.f, a2 = 0.f, a3 = 0.f;
    float a4 = 0.f, a5 = 0.f, a6 = 0.f, a7 = 0.f;

    for (int p = start + g; p < end; p += 8) {
        const ull r = __builtin_nontemporal_load(rec + p);
        const unsigned rlo = (unsigned)r;
        const unsigned wd  = (unsigned)(r >> 32);     // bf16 w, duplicated
        const unsigned i_  = rlo & 0xffffu;
        const unsigned j_  = rlo >> 16;
        const uint4 ui = *reinterpret_cast<const uint4*>(base + (size_t)i_ * 64);
        const uint4 uj = *reinterpret_cast<const uint4*>(base + (size_t)j_ * 64);
        DOT2(a0, __byte_perm(ui.x, uj.x, 0x5410u), wd)
        DOT2(a1, __byte_perm(ui.x, uj.x, 0x7632u), wd)
        DOT2(a2, __byte_perm(ui.y, uj.y, 0x5410u), wd)
        DOT2(a3, __byte_perm(ui.y, uj.y, 0x7632u), wd)
        DOT2(a4, __byte_perm(ui.z, uj.z, 0x5410u), wd)
        DOT2(a5, __byte_perm(ui.z, uj.z, 0x7632u), wd)
        DOT2(a6, __byte_perm(ui.w, uj.w, 0x5410u), wd)
        DOT2(a7, __byte_perm(ui.w, uj.w, 0x7632u), wd)
    }

#pragma unroll
    for (int m = 8; m <= 32; m <<= 1) {
        a0 += __shfl_xor(a0, m); a1 += __shfl_xor(a1, m);
        a2 += __shfl_xor(a2, m); a3 += __shfl_xor(a3, m);
        a4 += __shfl_xor(a4, m); a5 += __shfl_xor(a5, m);
        a6 += __shfl_xor(a6, m); a7 += __shfl_xor(a7, m);
    }

    if (g == 0) {
        uint4 o = {pack_bf16(a0, a1), pack_bf16(a2, a3),
                   pack_bf16(a4, a5), pack_bf16(a6, a7)};
        *reinterpret_cast<uint4*>(aggb + (size_t)n * 64 + cg * 32 + lane * 4) = o;
    }
}

// ---------------------------------------------------------------------------
// Proj (MFMA, validated R6/R8): out = aggb(bf16) @ W + bias.
// Block = 4 waves x 16 rows.
// ---------------------------------------------------------------------------
__global__ __launch_bounds__(256) void proj_kernel(
    const unsigned* __restrict__ aggb, const unsigned* __restrict__ Wt,
    const float* __restrict__ bias, float* __restrict__ out, int M) {
    const int wid = threadIdx.x >> 6;
    const int l   = threadIdx.x & 63;
    const int lr  = l & 15;
    const int lk  = l >> 4;
    const int row_base = blockIdx.x * 64 + wid * 16;

    int arow = row_base + lr;
    if (arow >= M) arow = M - 1;  // clamp; stores predicated

    const short8* __restrict__ A8 = reinterpret_cast<const short8*>(aggb);
    const short8* __restrict__ B8 = reinterpret_cast<const short8*>(Wt);

    floatx4 acc[8];
#pragma unroll
    for (int t = 0; t < 8; ++t) acc[t] = (floatx4){0.f, 0.f, 0.f, 0.f};

#pragma unroll
    for (int ks = 0; ks < 4; ++ks) {
        const short8 a = A8[(size_t)arow * 16 + ks * 4 + lk];
#pragma unroll
        for (int t = 0; t < 8; ++t) {
            const short8 bfr = B8[(size_t)(t * 16 + lr) * 16 + ks * 4 + lk];
            acc[t] = __builtin_amdgcn_mfma_f32_16x16x32_bf16(a, bfr, acc[t], 0, 0, 0);
        }
    }

#pragma unroll
    for (int t = 0; t < 8; ++t) {
        const float bcol = bias[t * 16 + lr];
#pragma unroll
        for (int r = 0; r < 4; ++r) {
            const int row = row_base + lk * 4 + r;
            if (row < M)
                out[(size_t)row * D + t * 16 + lr] = acc[t][r] + bcol;
        }
    }
}

// ---------------------------------------------------------------------------
extern "C" void kernel_launch(void* const* d_in, const int* in_sizes, int n_in,
                              void* d_out, int out_size, void* d_ws, size_t ws_size,
                              hipStream_t stream) {
    const float* F    = (const float*)d_in[0];
    const float* pw   = (const float*)d_in[1];
    const float* W    = (const float*)d_in[2];
    const float* bias = (const float*)d_in[3];
    const int*   pi   = (const int*)d_in[4];
    const int*   pj   = (const int*)d_in[5];
    const int*   nidx = (const int*)d_in[6];
    float* out = (float*)d_out;

    const int n_pairs = in_sizes[1];
    const int n_nodes = in_sizes[0] / D;

    // ws layout: aggb(bf16) | offs | rec | Wt | [Fb]
    const size_t aggb_bytes = (size_t)n_nodes * D * 2;
    const size_t offs_bytes = ((size_t)(n_nodes + 1) * 4 + 255) & ~(size_t)255;
    const size_t rec_bytes  = (size_t)n_pairs * 8;
    const size_t wt_bytes   = (size_t)D * (D / 2) * 4;
    const size_t fb_bytes   = (size_t)n_nodes * D * 2;

    char* pp = (char*)d_ws;
    unsigned* aggb = (unsigned*)pp;                pp += aggb_bytes;
    int*      offs = (int*)pp;                     pp += offs_bytes;
    ull*      rec  = (ull*)pp;                     pp += rec_bytes;
    unsigned* Wt   = (unsigned*)pp;                pp += wt_bytes;
    size_t used = (size_t)(pp - (char*)d_ws);
    unsigned* Fb = (ws_size >= used + fb_bytes)
                 ? (unsigned*)pp
                 : (unsigned*)d_out;  // proj writes out last; Fb dead by then

    const int B1 = (n_nodes * (D / 4) + 255) / 256;
    const int B2 = (n_pairs + 255) / 256;
    const int B3 = (D * (D / 2) + 255) / 256;
    prep_kernel<<<B1 + B2 + B3, 256, 0, stream>>>(F, pw, W, pi, pj, nidx,
                                                  Fb, rec, offs, Wt,
                                                  n_nodes, n_pairs);
    const int nb = (n_nodes + 3) / 4;  // 4 node-waves per block
    aggregate_kernel<<<nb * 2, 256, 0, stream>>>(Fb, rec, offs, aggb, n_nodes);
    proj_kernel<<<(n_nodes + 63) / 64, 256, 0, stream>>>(aggb, Wt, bias, out, n_nodes);
}

// Round 14
// 108.618 us; speedup vs baseline: 1.4155x; 1.1703x over previous
//
#include <hip/hip_runtime.h>

#define D 128
typedef unsigned long long ull;

typedef __attribute__((ext_vector_type(8))) short short8;   // 8 bf16 (4 VGPRs)
typedef __attribute__((ext_vector_type(4))) float floatx4;  // MFMA acc

__device__ __forceinline__ unsigned pack_bf16(float a, float b) {
    unsigned ua = __float_as_uint(a), ub = __float_as_uint(b);
    ua = (ua + 0x7fffu + ((ua >> 16) & 1u)) >> 16;   // RNE
    ub = (ub + 0x7fffu + ((ub >> 16) & 1u)) >> 16;
    return ua | (ub << 16);
}

// acc += pk.lo * wd.lo + pk.hi * wd.hi   (bf16 x bf16 -> f32 dot2)
#define DOT2(acc, pk, wd)                                                   \
    asm("v_dot2_f32_bf16 %0, %1, %2, %0" : "+v"(acc) : "v"(pk), "v"(wd));

// ---------------------------------------------------------------------------
// Prep: [A] features f32->bf16 [node][128] | [B] rec = i | j<<16 | wdup<<32
// (wdup = bf16(w) duplicated -> ready-made v_dot2 operand) + seg offsets |
// [C] W -> Wt bf16 transposed ([col][k-pairs]).
// ---------------------------------------------------------------------------
__global__ __launch_bounds__(256) void prep_kernel(
    const float* __restrict__ F, const float* __restrict__ pw,
    const float* __restrict__ W, const int* __restrict__ pi,
    const int* __restrict__ pj, const int* __restrict__ nidx,
    unsigned* __restrict__ Fb, ull* __restrict__ rec,
    int* __restrict__ offs, unsigned* __restrict__ Wt,
    int n_nodes, int n_pairs) {
    const int B1 = (n_nodes * (D / 4) + 255) / 256;
    const int B2 = (n_pairs + 255) / 256;
    const int b = blockIdx.x;
    if (b < B1) {                       // features -> bf16
        int t = b * 256 + threadIdx.x;
        if (t >= n_nodes * (D / 4)) return;
        float4 v = reinterpret_cast<const float4*>(F)[t];
        uint2 o = {pack_bf16(v.x, v.y), pack_bf16(v.z, v.w)};
        reinterpret_cast<uint2*>(Fb)[t] = o;
    } else if (b < B1 + B2) {           // records + offsets
        int p = (b - B1) * 256 + threadIdx.x;
        if (p >= n_pairs) return;
        unsigned wb = __float_as_uint(pw[p]);
        wb = (wb + 0x7fffu + ((wb >> 16) & 1u)) >> 16;
        unsigned wdup = wb | (wb << 16);
        rec[p] = (ull)((unsigned)pi[p] | ((unsigned)pj[p] << 16)) | ((ull)wdup << 32);
        int cur  = nidx[p];
        int prev = p ? nidx[p - 1] : -1;
        for (int n = prev + 1; n <= cur; ++n) offs[n] = p;
        if (p == n_pairs - 1)
            for (int n = cur + 1; n <= n_nodes; ++n) offs[n] = n_pairs;
    } else {                            // Wt[c][kk] = pack(W[2kk][c], W[2kk+1][c])
        int t = (b - B1 - B2) * 256 + threadIdx.x;
        if (t >= D * (D / 2)) return;
        int c = t >> 6, kk = t & 63;
        Wt[t] = pack_bf16(W[(2 * kk) * D + c], W[(2 * kk + 1) * D + c]);
    }
}

// ---------------------------------------------------------------------------
// Aggregate: R6's hoisted-record structure + R12's dot2 math.
// Wave per (node, half-row cg); cg = blockIdx&1 -> XCD-pinned alternating
// 128B lines. 8 groups x 8 lanes; lane gathers uint4 = 16 B per side.
// Per 64-pair chunk each lane loads ONE rec (off critical path; NT ok),
// __shfl broadcasts OUTSIDE the divergent guard (R13 bug: shfl source lane
// must be active — ds_bpermute from a masked lane is garbage).
// Inner: 8 v_perm [fj:fi] + 8 v_dot2 with wdup. Butterfly reduce;
// zero LDS / syncthreads. Output bf16.
// ---------------------------------------------------------------------------
__global__ __launch_bounds__(256) void aggregate_kernel(
    const unsigned* __restrict__ Fb, const ull* __restrict__ rec,
    const int* __restrict__ offs, unsigned* __restrict__ aggb, int n_nodes) {
    const int cg  = blockIdx.x & 1;
    const int wid = threadIdx.x >> 6;
    const int n   = (blockIdx.x >> 1) * 4 + wid;
    if (n >= n_nodes) return;
    const int start = offs[n];
    const int end   = offs[n + 1];
    const int lane  = threadIdx.x & 7;
    const int g     = (threadIdx.x >> 3) & 7;
    const int l64   = threadIdx.x & 63;

    const unsigned* __restrict__ base = Fb + cg * 32 + lane * 4;  // uint units

    float a0 = 0.f, a1 = 0.f, a2 = 0.f, a3 = 0.f;
    float a4 = 0.f, a5 = 0.f, a6 = 0.f, a7 = 0.f;

    for (int c0 = start; c0 < end; c0 += 64) {
        const int myp = c0 + l64;
        unsigned ijv = 0u, wdv = 0u;
        if (myp < end) {
            const ull rv = __builtin_nontemporal_load(rec + myp);
            ijv = (unsigned)rv;
            wdv = (unsigned)(rv >> 32);
        }
        const int nsteps = min(8, (end - c0 + 7) >> 3);
        for (int s = 0; s < nsteps; ++s) {
            const int src = s * 8 + g;
            // all 64 lanes execute the shfls (source lanes must be active)
            const unsigned r  = (unsigned)__shfl((int)ijv, src);
            const unsigned wd = (unsigned)__shfl((int)wdv, src);
            const int p = c0 + src;
            if (p < end) {
                const unsigned i_ = r & 0xffffu;
                const unsigned j_ = r >> 16;
                const uint4 ui = *reinterpret_cast<const uint4*>(base + (size_t)i_ * 64);
                const uint4 uj = *reinterpret_cast<const uint4*>(base + (size_t)j_ * 64);
                DOT2(a0, __byte_perm(ui.x, uj.x, 0x5410u), wd)
                DOT2(a1, __byte_perm(ui.x, uj.x, 0x7632u), wd)
                DOT2(a2, __byte_perm(ui.y, uj.y, 0x5410u), wd)
                DOT2(a3, __byte_perm(ui.y, uj.y, 0x7632u), wd)
                DOT2(a4, __byte_perm(ui.z, uj.z, 0x5410u), wd)
                DOT2(a5, __byte_perm(ui.z, uj.z, 0x7632u), wd)
                DOT2(a6, __byte_perm(ui.w, uj.w, 0x5410u), wd)
                DOT2(a7, __byte_perm(ui.w, uj.w, 0x7632u), wd)
            }
        }
    }

#pragma unroll
    for (int m = 8; m <= 32; m <<= 1) {
        a0 += __shfl_xor(a0, m); a1 += __shfl_xor(a1, m);
        a2 += __shfl_xor(a2, m); a3 += __shfl_xor(a3, m);
        a4 += __shfl_xor(a4, m); a5 += __shfl_xor(a5, m);
        a6 += __shfl_xor(a6, m); a7 += __shfl_xor(a7, m);
    }

    if (g == 0) {
        uint4 o = {pack_bf16(a0, a1), pack_bf16(a2, a3),
                   pack_bf16(a4, a5), pack_bf16(a6, a7)};
        *reinterpret_cast<uint4*>(aggb + (size_t)n * 64 + cg * 32 + lane * 4) = o;
    }
}

// ---------------------------------------------------------------------------
// Proj (MFMA, validated R6/R8): out = aggb(bf16) @ W + bias.
// Block = 4 waves x 16 rows.
// ---------------------------------------------------------------------------
__global__ __launch_bounds__(256) void proj_kernel(
    const unsigned* __restrict__ aggb, const unsigned* __restrict__ Wt,
    const float* __restrict__ bias, float* __restrict__ out, int M) {
    const int wid = threadIdx.x >> 6;
    const int l   = threadIdx.x & 63;
    const int lr  = l & 15;
    const int lk  = l >> 4;
    const int row_base = blockIdx.x * 64 + wid * 16;

    int arow = row_base + lr;
    if (arow >= M) arow = M - 1;  // clamp; stores predicated

    const short8* __restrict__ A8 = reinterpret_cast<const short8*>(aggb);
    const short8* __restrict__ B8 = reinterpret_cast<const short8*>(Wt);

    floatx4 acc[8];
#pragma unroll
    for (int t = 0; t < 8; ++t) acc[t] = (floatx4){0.f, 0.f, 0.f, 0.f};

#pragma unroll
    for (int ks = 0; ks < 4; ++ks) {
        const short8 a = A8[(size_t)arow * 16 + ks * 4 + lk];
#pragma unroll
        for (int t = 0; t < 8; ++t) {
            const short8 bfr = B8[(size_t)(t * 16 + lr) * 16 + ks * 4 + lk];
            acc[t] = __builtin_amdgcn_mfma_f32_16x16x32_bf16(a, bfr, acc[t], 0, 0, 0);
        }
    }

#pragma unroll
    for (int t = 0; t < 8; ++t) {
        const float bcol = bias[t * 16 + lr];
#pragma unroll
        for (int r = 0; r < 4; ++r) {
            const int row = row_base + lk * 4 + r;
            if (row < M)
                out[(size_t)row * D + t * 16 + lr] = acc[t][r] + bcol;
        }
    }
}

// ---------------------------------------------------------------------------
extern "C" void kernel_launch(void* const* d_in, const int* in_sizes, int n_in,
                              void* d_out, int out_size, void* d_ws, size_t ws_size,
                              hipStream_t stream) {
    const float* F    = (const float*)d_in[0];
    const float* pw   = (const float*)d_in[1];
    const float* W    = (const float*)d_in[2];
    const float* bias = (const float*)d_in[3];
    const int*   pi   = (const int*)d_in[4];
    const int*   pj   = (const int*)d_in[5];
    const int*   nidx = (const int*)d_in[6];
    float* out = (float*)d_out;

    const int n_pairs = in_sizes[1];
    const int n_nodes = in_sizes[0] / D;

    // ws layout: aggb(bf16) | offs | rec | Wt | [Fb]
    const size_t aggb_bytes = (size_t)n_nodes * D * 2;
    const size_t offs_bytes = ((size_t)(n_nodes + 1) * 4 + 255) & ~(size_t)255;
    const size_t rec_bytes  = (size_t)n_pairs * 8;
    const size_t wt_bytes   = (size_t)D * (D / 2) * 4;
    const size_t fb_bytes   = (size_t)n_nodes * D * 2;

    char* pp = (char*)d_ws;
    unsigned* aggb = (unsigned*)pp;                pp += aggb_bytes;
    int*      offs = (int*)pp;                     pp += offs_bytes;
    ull*      rec  = (ull*)pp;                     pp += rec_bytes;
    unsigned* Wt   = (unsigned*)pp;                pp += wt_bytes;
    size_t used = (size_t)(pp - (char*)d_ws);
    unsigned* Fb = (ws_size >= used + fb_bytes)
                 ? (unsigned*)pp
                 : (unsigned*)d_out;  // proj writes out last; Fb dead by then

    const int B1 = (n_nodes * (D / 4) + 255) / 256;
    const int B2 = (n_pairs + 255) / 256;
    const int B3 = (D * (D / 2) + 255) / 256;
    prep_kernel<<<B1 + B2 + B3, 256, 0, stream>>>(F, pw, W, pi, pj, nidx,
                                                  Fb, rec, offs, Wt,
                                                  n_nodes, n_pairs);
    const int nb = (n_nodes + 3) / 4;  // 4 node-waves per block
    aggregate_kernel<<<nb * 2, 256, 0, stream>>>(Fb, rec, offs, aggb, n_nodes);
    proj_kernel<<<(n_nodes + 63) / 64, 256, 0, stream>>>(aggb, Wt, bias, out, n_nodes);
}

// Round 15
// 107.779 us; speedup vs baseline: 1.4265x; 1.0078x over previous
//
#include <hip/hip_runtime.h>

#define D 128
typedef unsigned long long ull;

typedef __attribute__((ext_vector_type(8))) short short8;   // 8 bf16 (4 VGPRs)
typedef __attribute__((ext_vector_type(4))) float floatx4;  // MFMA acc

__device__ __forceinline__ unsigned pack_bf16(float a, float b) {
    unsigned ua = __float_as_uint(a), ub = __float_as_uint(b);
    ua = (ua + 0x7fffu + ((ua >> 16) & 1u)) >> 16;   // RNE
    ub = (ub + 0x7fffu + ((ub >> 16) & 1u)) >> 16;
    return ua | (ub << 16);
}

// acc += pk.lo * wd.lo + pk.hi * wd.hi   (bf16 x bf16 -> f32 dot2)
#define DOT2(acc, pk, wd)                                                   \
    asm("v_dot2_f32_bf16 %0, %1, %2, %0" : "+v"(acc) : "v"(pk), "v"(wd));

// ---------------------------------------------------------------------------
// Prep: [A] features f32->bf16 [node][128] | [B] rec = i | j<<16 | wdup<<32
// + seg offsets | [C] W -> Wt bf16 transposed ([col][k-pairs]).
// ---------------------------------------------------------------------------
__global__ __launch_bounds__(256) void prep_kernel(
    const float* __restrict__ F, const float* __restrict__ pw,
    const float* __restrict__ W, const int* __restrict__ pi,
    const int* __restrict__ pj, const int* __restrict__ nidx,
    unsigned* __restrict__ Fb, ull* __restrict__ rec,
    int* __restrict__ offs, unsigned* __restrict__ Wt,
    int n_nodes, int n_pairs) {
    const int B1 = (n_nodes * (D / 4) + 255) / 256;
    const int B2 = (n_pairs + 255) / 256;
    const int b = blockIdx.x;
    if (b < B1) {                       // features -> bf16
        int t = b * 256 + threadIdx.x;
        if (t >= n_nodes * (D / 4)) return;
        float4 v = reinterpret_cast<const float4*>(F)[t];
        uint2 o = {pack_bf16(v.x, v.y), pack_bf16(v.z, v.w)};
        reinterpret_cast<uint2*>(Fb)[t] = o;
    } else if (b < B1 + B2) {           // records + offsets
        int p = (b - B1) * 256 + threadIdx.x;
        if (p >= n_pairs) return;
        unsigned wb = __float_as_uint(pw[p]);
        wb = (wb + 0x7fffu + ((wb >> 16) & 1u)) >> 16;
        unsigned wdup = wb | (wb << 16);
        rec[p] = (ull)((unsigned)pi[p] | ((unsigned)pj[p] << 16)) | ((ull)wdup << 32);
        int cur  = nidx[p];
        int prev = p ? nidx[p - 1] : -1;
        for (int n = prev + 1; n <= cur; ++n) offs[n] = p;
        if (p == n_pairs - 1)
            for (int n = cur + 1; n <= n_nodes; ++n) offs[n] = n_pairs;
    } else {                            // Wt[c][kk] = pack(W[2kk][c], W[2kk+1][c])
        int t = (b - B1 - B2) * 256 + threadIdx.x;
        if (t >= D * (D / 2)) return;
        int c = t >> 6, kk = t & 63;
        Wt[t] = pack_bf16(W[(2 * kk) * D + c], W[(2 * kk + 1) * D + c]);
    }
}

// ---------------------------------------------------------------------------
// Aggregate: R14 math + depth-3 software pipeline (R14 post-mortem: VGPR=24
// forces gather reg-reuse -> WAR serialization -> ~2 loads in flight/wave).
// Wave per (node, half-row cg); cg = blockIdx&1 (XCD-pinned, proven).
// 8 groups x 8 lanes; lane gathers uint4 = 16 B per side. Flat stride-8
// per-group loop; rec loads CACHED (R12: NT-in-chain costs ~200cy/iter);
// stage C issued before stage A is consumed. Named per-stage registers.
// ---------------------------------------------------------------------------
#define LOADSTAGE(sfx, pp)                                                    \
    {                                                                         \
        const ull rv_ = rec[pp];                                              \
        wd##sfx = (unsigned)(rv_ >> 32);                                      \
        const unsigned ij_ = (unsigned)rv_;                                   \
        const size_t i_ = (size_t)(ij_ & 0xffffu);                            \
        const size_t j_ = (size_t)(ij_ >> 16);                                \
        ui##sfx = *reinterpret_cast<const uint4*>(base + i_ * 64);            \
        uj##sfx = *reinterpret_cast<const uint4*>(base + j_ * 64);            \
    }

#define CONSUME(sfx)                                                          \
    {                                                                         \
        DOT2(a0, __byte_perm(ui##sfx.x, uj##sfx.x, 0x5410u), wd##sfx)         \
        DOT2(a1, __byte_perm(ui##sfx.x, uj##sfx.x, 0x7632u), wd##sfx)         \
        DOT2(a2, __byte_perm(ui##sfx.y, uj##sfx.y, 0x5410u), wd##sfx)         \
        DOT2(a3, __byte_perm(ui##sfx.y, uj##sfx.y, 0x7632u), wd##sfx)         \
        DOT2(a4, __byte_perm(ui##sfx.z, uj##sfx.z, 0x5410u), wd##sfx)         \
        DOT2(a5, __byte_perm(ui##sfx.z, uj##sfx.z, 0x7632u), wd##sfx)         \
        DOT2(a6, __byte_perm(ui##sfx.w, uj##sfx.w, 0x5410u), wd##sfx)         \
        DOT2(a7, __byte_perm(ui##sfx.w, uj##sfx.w, 0x7632u), wd##sfx)         \
    }

__global__ __launch_bounds__(256) void aggregate_kernel(
    const unsigned* __restrict__ Fb, const ull* __restrict__ rec,
    const int* __restrict__ offs, unsigned* __restrict__ aggb, int n_nodes) {
    const int cg  = blockIdx.x & 1;
    const int wid = threadIdx.x >> 6;
    const int n   = (blockIdx.x >> 1) * 4 + wid;
    if (n >= n_nodes) return;
    const int start = offs[n];
    const int end   = offs[n + 1];
    const int lane  = threadIdx.x & 7;
    const int g     = (threadIdx.x >> 3) & 7;

    const unsigned* __restrict__ base = Fb + cg * 32 + lane * 4;  // uint units

    float a0 = 0.f, a1 = 0.f, a2 = 0.f, a3 = 0.f;
    float a4 = 0.f, a5 = 0.f, a6 = 0.f, a7 = 0.f;

    uint4 uiA, ujA, uiB, ujB, uiC, ujC;
    unsigned wdA, wdB, wdC;

    int p = start + g;
    const bool vA0 = p < end;
    const bool vB0 = p + 8 < end;
    if (vA0) LOADSTAGE(A, p)
    if (vB0) LOADSTAGE(B, p + 8)

    while (p + 16 < end) {
        LOADSTAGE(C, p + 16)
        CONSUME(A)
        uiA = uiB; ujA = ujB; wdA = wdB;
        uiB = uiC; ujB = ujC; wdB = wdC;
        p += 8;
    }
    if (p < end)     CONSUME(A)
    if (p + 8 < end) CONSUME(B)

#pragma unroll
    for (int m = 8; m <= 32; m <<= 1) {
        a0 += __shfl_xor(a0, m); a1 += __shfl_xor(a1, m);
        a2 += __shfl_xor(a2, m); a3 += __shfl_xor(a3, m);
        a4 += __shfl_xor(a4, m); a5 += __shfl_xor(a5, m);
        a6 += __shfl_xor(a6, m); a7 += __shfl_xor(a7, m);
    }

    if (g == 0) {
        uint4 o = {pack_bf16(a0, a1), pack_bf16(a2, a3),
                   pack_bf16(a4, a5), pack_bf16(a6, a7)};
        *reinterpret_cast<uint4*>(aggb + (size_t)n * 64 + cg * 32 + lane * 4) = o;
    }
}

// ---------------------------------------------------------------------------
// Proj (MFMA, validated R6/R8): out = aggb(bf16) @ W + bias.
// Block = 4 waves x 16 rows.
// ---------------------------------------------------------------------------
__global__ __launch_bounds__(256) void proj_kernel(
    const unsigned* __restrict__ aggb, const unsigned* __restrict__ Wt,
    const float* __restrict__ bias, float* __restrict__ out, int M) {
    const int wid = threadIdx.x >> 6;
    const int l   = threadIdx.x & 63;
    const int lr  = l & 15;
    const int lk  = l >> 4;
    const int row_base = blockIdx.x * 64 + wid * 16;

    int arow = row_base + lr;
    if (arow >= M) arow = M - 1;  // clamp; stores predicated

    const short8* __restrict__ A8 = reinterpret_cast<const short8*>(aggb);
    const short8* __restrict__ B8 = reinterpret_cast<const short8*>(Wt);

    floatx4 acc[8];
#pragma unroll
    for (int t = 0; t < 8; ++t) acc[t] = (floatx4){0.f, 0.f, 0.f, 0.f};

#pragma unroll
    for (int ks = 0; ks < 4; ++ks) {
        const short8 a = A8[(size_t)arow * 16 + ks * 4 + lk];
#pragma unroll
        for (int t = 0; t < 8; ++t) {
            const short8 bfr = B8[(size_t)(t * 16 + lr) * 16 + ks * 4 + lk];
            acc[t] = __builtin_amdgcn_mfma_f32_16x16x32_bf16(a, bfr, acc[t], 0, 0, 0);
        }
    }

#pragma unroll
    for (int t = 0; t < 8; ++t) {
        const float bcol = bias[t * 16 + lr];
#pragma unroll
        for (int r = 0; r < 4; ++r) {
            const int row = row_base + lk * 4 + r;
            if (row < M)
                out[(size_t)row * D + t * 16 + lr] = acc[t][r] + bcol;
        }
    }
}

// ---------------------------------------------------------------------------
extern "C" void kernel_launch(void* const* d_in, const int* in_sizes, int n_in,
                              void* d_out, int out_size, void* d_ws, size_t ws_size,
                              hipStream_t stream) {
    const float* F    = (const float*)d_in[0];
    const float* pw   = (const float*)d_in[1];
    const float* W    = (const float*)d_in[2];
    const float* bias = (const float*)d_in[3];
    const int*   pi   = (const int*)d_in[4];
    const int*   pj   = (const int*)d_in[5];
    const int*   nidx = (const int*)d_in[6];
    float* out = (float*)d_out;

    const int n_pairs = in_sizes[1];
    const int n_nodes = in_sizes[0] / D;

    // ws layout: aggb(bf16) | offs | rec | Wt | [Fb]
    const size_t aggb_bytes = (size_t)n_nodes * D * 2;
    const size_t offs_bytes = ((size_t)(n_nodes + 1) * 4 + 255) & ~(size_t)255;
    const size_t rec_bytes  = (size_t)n_pairs * 8;
    const size_t wt_bytes   = (size_t)D * (D / 2) * 4;
    const size_t fb_bytes   = (size_t)n_nodes * D * 2;

    char* pp = (char*)d_ws;
    unsigned* aggb = (unsigned*)pp;                pp += aggb_bytes;
    int*      offs = (int*)pp;                     pp += offs_bytes;
    ull*      rec  = (ull*)pp;                     pp += rec_bytes;
    unsigned* Wt   = (unsigned*)pp;                pp += wt_bytes;
    size_t used = (size_t)(pp - (char*)d_ws);
    unsigned* Fb = (ws_size >= used + fb_bytes)
                 ? (unsigned*)pp
                 : (unsigned*)d_out;  // proj writes out last; Fb dead by then

    const int B1 = (n_nodes * (D / 4) + 255) / 256;
    const int B2 = (n_pairs + 255) / 256;
    const int B3 = (D * (D / 2) + 255) / 256;
    prep_kernel<<<B1 + B2 + B3, 256, 0, stream>>>(F, pw, W, pi, pj, nidx,
                                                  Fb, rec, offs, Wt,
                                                  n_nodes, n_pairs);
    const int nb = (n_nodes + 3) / 4;  // 4 node-waves per block
    aggregate_kernel<<<nb * 2, 256, 0, stream>>>(Fb, rec, offs, aggb, n_nodes);
    proj_kernel<<<(n_nodes + 63) / 64, 256, 0, stream>>>(aggb, Wt, bias, out, n_nodes);
}

// Round 16
// 100.005 us; speedup vs baseline: 1.5374x; 1.0777x over previous
//
#include <hip/hip_runtime.h>

#define D 128
typedef unsigned long long ull;

typedef __attribute__((ext_vector_type(8))) short short8;   // 8 bf16 (4 VGPRs)
typedef __attribute__((ext_vector_type(4))) float floatx4;  // MFMA acc

__device__ __forceinline__ unsigned pack_bf16(float a, float b) {
    unsigned ua = __float_as_uint(a), ub = __float_as_uint(b);
    ua = (ua + 0x7fffu + ((ua >> 16) & 1u)) >> 16;   // RNE
    ub = (ub + 0x7fffu + ((ub >> 16) & 1u)) >> 16;
    return ua | (ub << 16);
}

// acc += pk.lo * wd.lo + pk.hi * wd.hi   (bf16 x bf16 -> f32 dot2)
#define DOT2(acc, pk, wd)                                                   \
    asm("v_dot2_f32_bf16 %0, %1, %2, %0" : "+v"(acc) : "v"(pk), "v"(wd));

// ---------------------------------------------------------------------------
// Prep (lean): [A] features f32->bf16 [node][128] | [B] seg offsets only |
// [C] W -> Wt bf16 transposed ([col][k-pairs]). No rec build (aggregate is
// line-touch-bound, streaming index reads ride free — R15 analysis).
// ---------------------------------------------------------------------------
__global__ __launch_bounds__(256) void prep_kernel(
    const float* __restrict__ F, const float* __restrict__ W,
    const int* __restrict__ nidx,
    unsigned* __restrict__ Fb, int* __restrict__ offs, unsigned* __restrict__ Wt,
    int n_nodes, int n_pairs) {
    const int B1 = (n_nodes * (D / 4) + 255) / 256;
    const int B2 = (n_pairs + 255) / 256;
    const int b = blockIdx.x;
    if (b < B1) {                       // features -> bf16
        int t = b * 256 + threadIdx.x;
        if (t >= n_nodes * (D / 4)) return;
        float4 v = reinterpret_cast<const float4*>(F)[t];
        uint2 o = {pack_bf16(v.x, v.y), pack_bf16(v.z, v.w)};
        reinterpret_cast<uint2*>(Fb)[t] = o;
    } else if (b < B1 + B2) {           // segment offsets
        int p = (b - B1) * 256 + threadIdx.x;
        if (p >= n_pairs) return;
        int cur  = nidx[p];
        int prev = p ? nidx[p - 1] : -1;
        for (int n = prev + 1; n <= cur; ++n) offs[n] = p;
        if (p == n_pairs - 1)
            for (int n = cur + 1; n <= n_nodes; ++n) offs[n] = n_pairs;
    } else {                            // Wt[c][kk] = pack(W[2kk][c], W[2kk+1][c])
        int t = (b - B1 - B2) * 256 + threadIdx.x;
        if (t >= D * (D / 2)) return;
        int c = t >> 6, kk = t & 63;
        Wt[t] = pack_bf16(W[(2 * kk) * D + c], W[(2 * kk + 1) * D + c]);
    }
}

// ---------------------------------------------------------------------------
// Aggregate (R14 structure — at the L2 scattered-line service floor).
// Wave per (node, half-row cg); cg = blockIdx&1 -> XCD-pinned alternating
// 128B lines. 8 groups x 8 lanes; lane gathers uint4 = 16 B per side.
// Per 64-pair chunk each lane loads pi/pj/pw directly (coalesced, off
// critical path) and packs ijv/wdup in-register (~6 VALU/chunk); __shfl
// broadcasts OUTSIDE the divergent guard (R13 lesson). Inner: 8 v_perm
// [fj:fi] + 8 v_dot2 with wdup. Butterfly reduce; zero LDS/syncthreads.
// ---------------------------------------------------------------------------
__global__ __launch_bounds__(256) void aggregate_kernel(
    const unsigned* __restrict__ Fb, const int* __restrict__ pi,
    const int* __restrict__ pj, const float* __restrict__ pw,
    const int* __restrict__ offs, unsigned* __restrict__ aggb, int n_nodes) {
    const int cg  = blockIdx.x & 1;
    const int wid = threadIdx.x >> 6;
    const int n   = (blockIdx.x >> 1) * 4 + wid;
    if (n >= n_nodes) return;
    const int start = offs[n];
    const int end   = offs[n + 1];
    const int lane  = threadIdx.x & 7;
    const int g     = (threadIdx.x >> 3) & 7;
    const int l64   = threadIdx.x & 63;

    const unsigned* __restrict__ base = Fb + cg * 32 + lane * 4;  // uint units

    float a0 = 0.f, a1 = 0.f, a2 = 0.f, a3 = 0.f;
    float a4 = 0.f, a5 = 0.f, a6 = 0.f, a7 = 0.f;

    for (int c0 = start; c0 < end; c0 += 64) {
        const int myp = c0 + l64;
        unsigned ijv = 0u, wdv = 0u;
        if (myp < end) {
            const unsigned iv = (unsigned)pi[myp];
            const unsigned jv = (unsigned)pj[myp];
            unsigned wb = __float_as_uint(pw[myp]);
            wb = (wb + 0x7fffu + ((wb >> 16) & 1u)) >> 16;   // RNE to bf16
            ijv = iv | (jv << 16);
            wdv = wb | (wb << 16);
        }
        const int nsteps = min(8, (end - c0 + 7) >> 3);
        for (int s = 0; s < nsteps; ++s) {
            const int src = s * 8 + g;
            // all 64 lanes execute the shfls (source lanes must be active)
            const unsigned r  = (unsigned)__shfl((int)ijv, src);
            const unsigned wd = (unsigned)__shfl((int)wdv, src);
            const int p = c0 + src;
            if (p < end) {
                const unsigned i_ = r & 0xffffu;
                const unsigned j_ = r >> 16;
                const uint4 ui = *reinterpret_cast<const uint4*>(base + (size_t)i_ * 64);
                const uint4 uj = *reinterpret_cast<const uint4*>(base + (size_t)j_ * 64);
                DOT2(a0, __byte_perm(ui.x, uj.x, 0x5410u), wd)
                DOT2(a1, __byte_perm(ui.x, uj.x, 0x7632u), wd)
                DOT2(a2, __byte_perm(ui.y, uj.y, 0x5410u), wd)
                DOT2(a3, __byte_perm(ui.y, uj.y, 0x7632u), wd)
                DOT2(a4, __byte_perm(ui.z, uj.z, 0x5410u), wd)
                DOT2(a5, __byte_perm(ui.z, uj.z, 0x7632u), wd)
                DOT2(a6, __byte_perm(ui.w, uj.w, 0x5410u), wd)
                DOT2(a7, __byte_perm(ui.w, uj.w, 0x7632u), wd)
            }
        }
    }

#pragma unroll
    for (int m = 8; m <= 32; m <<= 1) {
        a0 += __shfl_xor(a0, m); a1 += __shfl_xor(a1, m);
        a2 += __shfl_xor(a2, m); a3 += __shfl_xor(a3, m);
        a4 += __shfl_xor(a4, m); a5 += __shfl_xor(a5, m);
        a6 += __shfl_xor(a6, m); a7 += __shfl_xor(a7, m);
    }

    if (g == 0) {
        uint4 o = {pack_bf16(a0, a1), pack_bf16(a2, a3),
                   pack_bf16(a4, a5), pack_bf16(a6, a7)};
        *reinterpret_cast<uint4*>(aggb + (size_t)n * 64 + cg * 32 + lane * 4) = o;
    }
}

// ---------------------------------------------------------------------------
// Proj (MFMA, validated R6/R8): out = aggb(bf16) @ W + bias.
// Block = 4 waves x 16 rows.
// ---------------------------------------------------------------------------
__global__ __launch_bounds__(256) void proj_kernel(
    const unsigned* __restrict__ aggb, const unsigned* __restrict__ Wt,
    const float* __restrict__ bias, float* __restrict__ out, int M) {
    const int wid = threadIdx.x >> 6;
    const int l   = threadIdx.x & 63;
    const int lr  = l & 15;
    const int lk  = l >> 4;
    const int row_base = blockIdx.x * 64 + wid * 16;

    int arow = row_base + lr;
    if (arow >= M) arow = M - 1;  // clamp; stores predicated

    const short8* __restrict__ A8 = reinterpret_cast<const short8*>(aggb);
    const short8* __restrict__ B8 = reinterpret_cast<const short8*>(Wt);

    floatx4 acc[8];
#pragma unroll
    for (int t = 0; t < 8; ++t) acc[t] = (floatx4){0.f, 0.f, 0.f, 0.f};

#pragma unroll
    for (int ks = 0; ks < 4; ++ks) {
        const short8 a = A8[(size_t)arow * 16 + ks * 4 + lk];
#pragma unroll
        for (int t = 0; t < 8; ++t) {
            const short8 bfr = B8[(size_t)(t * 16 + lr) * 16 + ks * 4 + lk];
            acc[t] = __builtin_amdgcn_mfma_f32_16x16x32_bf16(a, bfr, acc[t], 0, 0, 0);
        }
    }

#pragma unroll
    for (int t = 0; t < 8; ++t) {
        const float bcol = bias[t * 16 + lr];
#pragma unroll
        for (int r = 0; r < 4; ++r) {
            const int row = row_base + lk * 4 + r;
            if (row < M)
                out[(size_t)row * D + t * 16 + lr] = acc[t][r] + bcol;
        }
    }
}

// ---------------------------------------------------------------------------
extern "C" void kernel_launch(void* const* d_in, const int* in_sizes, int n_in,
                              void* d_out, int out_size, void* d_ws, size_t ws_size,
                              hipStream_t stream) {
    const float* F    = (const float*)d_in[0];
    const float* pw   = (const float*)d_in[1];
    const float* W    = (const float*)d_in[2];
    const float* bias = (const float*)d_in[3];
    const int*   pi   = (const int*)d_in[4];
    const int*   pj   = (const int*)d_in[5];
    const int*   nidx = (const int*)d_in[6];
    float* out = (float*)d_out;

    const int n_pairs = in_sizes[1];
    const int n_nodes = in_sizes[0] / D;

    // ws layout: aggb(bf16) | offs | Wt | [Fb]
    const size_t aggb_bytes = (size_t)n_nodes * D * 2;
    const size_t offs_bytes = ((size_t)(n_nodes + 1) * 4 + 255) & ~(size_t)255;
    const size_t wt_bytes   = (size_t)D * (D / 2) * 4;
    const size_t fb_bytes   = (size_t)n_nodes * D * 2;

    char* pp = (char*)d_ws;
    unsigned* aggb = (unsigned*)pp;   pp += aggb_bytes;
    int*      offs = (int*)pp;        pp += offs_bytes;
    unsigned* Wt   = (unsigned*)pp;   pp += wt_bytes;
    size_t used = (size_t)(pp - (char*)d_ws);
    unsigned* Fb = (ws_size >= used + fb_bytes)
                 ? (unsigned*)pp
                 : (unsigned*)d_out;  // proj writes out last; Fb dead by then

    const int B1 = (n_nodes * (D / 4) + 255) / 256;
    const int B2 = (n_pairs + 255) / 256;
    const int B3 = (D * (D / 2) + 255) / 256;
    prep_kernel<<<B1 + B2 + B3, 256, 0, stream>>>(F, W, nidx, Fb, offs, Wt,
                                                  n_nodes, n_pairs);
    const int nb = (n_nodes + 3) / 4;  // 4 node-waves per block
    aggregate_kernel<<<nb * 2, 256, 0, stream>>>(Fb, pi, pj, pw, offs, aggb, n_nodes);
    proj_kernel<<<(n_nodes + 63) / 64, 256, 0, stream>>>(aggb, Wt, bias, out, n_nodes);
}